// Round 14
// baseline (370.349 us; speedup 1.0000x reference)
//
#include <hip/hip_runtime.h>
#include <hip/hip_bf16.h>
#include <hip/hip_cooperative_groups.h>

namespace cg = cooperative_groups;

#define NSLOT 8
#define SDIM 256
#define FDIM 128
#define NHEAD 4
#define HDIM 64
#define NPOS 4096

typedef short v8s __attribute__((ext_vector_type(8)));
typedef short v4s __attribute__((ext_vector_type(4)));
typedef float v4f __attribute__((ext_vector_type(4)));

__device__ __forceinline__ unsigned short f2bf(float x) {
    __hip_bfloat16 h = __float2bfloat16(x);
    unsigned short u; __builtin_memcpy(&u, &h, 2); return u;
}
__device__ __forceinline__ float bfr2f(unsigned short u) {
    __hip_bfloat16 h; __builtin_memcpy(&h, &u, 2); return __bfloat162float(h);
}
__device__ __forceinline__ void split2(float x, unsigned short& hi, unsigned short& lo) {
    hi = f2bf(x);
    lo = f2bf(x - bfr2f(hi));
}

// ---------------- K1 (fused prep, 592 blocks) — unchanged from round 13 ----
__global__ __launch_bounds__(256) void k_prep(
    const float* __restrict__ slots,
    const float* __restrict__ Wq, const float* __restrict__ bq,
    const float* __restrict__ g_pre, const float* __restrict__ b_pre,
    const float* __restrict__ Wk, const float* __restrict__ bk,
    const float* __restrict__ W1, const float* __restrict__ W2,
    const float* __restrict__ W_ih, const float* __restrict__ W_hh,
    const float* __restrict__ Wv,
    unsigned short* __restrict__ qkT_ws, float* __restrict__ qb_ws,
    unsigned short* __restrict__ W1Th, unsigned short* __restrict__ W1Tl,
    unsigned short* __restrict__ W2Th, unsigned short* __restrict__ W2Tl,
    unsigned short* __restrict__ WihH, unsigned short* __restrict__ WihL,
    unsigned short* __restrict__ WhhH, unsigned short* __restrict__ WhhL,
    unsigned short* __restrict__ WvTH, unsigned short* __restrict__ WvTl,
    float* __restrict__ agg_ws)
{
    int blk = blockIdx.x, t = threadIdx.x;
    __shared__ float s_ln[8 * 256];
    __shared__ float q_l[32 * 65];
    __shared__ float red1[256], red2[256];
    __shared__ float tl[32][33];

    if (blk >= 560) {                // WvT transpose+split
        int id3 = blk - 560;
        int k0 = (id3 & 3) * 32, n0 = (id3 >> 2) * 32;
        for (int i = 0; i < 4; i++) {
            int idx = i * 256 + t, r = idx >> 5, c = idx & 31;
            tl[r][c] = Wv[(size_t)(k0 + r) * 256 + n0 + c];
        }
        __syncthreads();
        for (int i = 0; i < 4; i++) {
            int idx = i * 256 + t, r = idx >> 5, c = idx & 31;
            unsigned short hi, lo; split2(tl[c][r], hi, lo);
            WvTH[(size_t)(n0 + r) * 128 + k0 + c] = hi;
            WvTl[(size_t)(n0 + r) * 128 + k0 + c] = lo;
        }
        return;
    }
    if (blk >= 512) {                // gate-weight split: 768 rows each
        int id2 = blk - 512;
        const float* src; unsigned short *dh, *dl; int r0;
        if (id2 < 24) { src = W_ih; dh = WihH; dl = WihL; r0 = id2 * 32; }
        else          { src = W_hh; dh = WhhH; dl = WhhL; r0 = (id2 - 24) * 32; }
        for (int i = 0; i < 32; i++) {
            size_t idx = (size_t)(r0 + i) * 256 + t;
            unsigned short hi, lo; split2(src[idx], hi, lo);
            dh[idx] = hi; dl[idx] = lo;
        }
        return;
    }
    if (blk >= 256) {                // W1/W2 transpose+split
        int id = blk - 256;
        const float* src; unsigned short *dh, *dl; int N, K, k0, n0;
        if (id < 128) { src = W1; dh = W1Th; dl = W1Tl; N = 512; K = 256;
                        k0 = (id >> 4) * 32; n0 = (id & 15) * 32; }
        else          { int i2 = id - 128; src = W2; dh = W2Th; dl = W2Tl; N = 256; K = 512;
                        k0 = (i2 >> 3) * 32; n0 = (i2 & 7) * 32; }
        for (int i = 0; i < 4; i++) {
            int idx = i * 256 + t, r = idx >> 5, c = idx & 31;
            tl[r][c] = src[(size_t)(k0 + r) * N + n0 + c];
        }
        __syncthreads();
        for (int i = 0; i < 4; i++) {
            int idx = i * 256 + t, r = idx >> 5, c = idx & 31;
            unsigned short hi, lo; split2(tl[c][r], hi, lo);
            dh[(size_t)(n0 + r) * K + k0 + c] = hi;
            dl[(size_t)(n0 + r) * K + k0 + c] = lo;
        }
        return;
    }

    // ---- per-batch prep ----
    int b = blk >> 3, chunk = blk & 7;
    if (chunk == 0)
        for (int i = 0; i < 8; i++) agg_ws[b * 2048 + i * 256 + t] = 0.0f;

    int s8 = t >> 5, lane = t & 31;
    float xv[8], sum = 0.0f, sq = 0.0f;
    for (int u = 0; u < 8; u++) {
        float x = slots[(b * 8 + s8) * 256 + lane * 8 + u];
        xv[u] = x; sum += x; sq += x * x;
    }
    red1[t] = sum; red2[t] = sq;
    __syncthreads();
    for (int o = 16; o > 0; o >>= 1) {
        if (lane < o) { red1[t] += red1[t + o]; red2[t] += red2[t + o]; }
        __syncthreads();
    }
    float mu  = red1[s8 * 32] * (1.0f / 256);
    float var = red2[s8 * 32] * (1.0f / 256) - mu * mu;
    float rstd = rsqrtf(var + 1e-5f);
    for (int u = 0; u < 8; u++) {
        int j = lane * 8 + u;
        s_ln[s8 * 256 + j] = (xv[u] - mu) * rstd * g_pre[j] + b_pre[j];
    }
    __syncthreads();

    float qa[8];
    #pragma unroll
    for (int s = 0; s < 8; s++) qa[s] = bq[t];
    for (int k = 0; k < 256; k++) {
        float wq = Wq[k * 256 + t];
        #pragma unroll
        for (int s = 0; s < 8; s++) qa[s] += s_ln[s * 256 + k] * wq;
    }
    int h = t >> 6, d = t & 63;
    for (int s = 0; s < 8; s++) q_l[(s * 4 + h) * 65 + d] = qa[s];
    __syncthreads();

    int hs = t & 31, hh = hs >> 3, si = hs & 7, c0 = t >> 5;
    const float* qrow = &q_l[(si * 4 + hh) * 65];
    for (int i = 0; i < 2; i++) {
        int c = chunk * 16 + i * 8 + c0;
        const float4* wk4 = (const float4*)&Wk[c * 256 + hh * 64];
        float acc = 0.0f;
        #pragma unroll
        for (int d4 = 0; d4 < 16; d4++) {
            float4 w = wk4[d4];
            acc += w.x * qrow[d4 * 4] + w.y * qrow[d4 * 4 + 1]
                 + w.z * qrow[d4 * 4 + 2] + w.w * qrow[d4 * 4 + 3];
        }
        qkT_ws[(b * 32 + hs) * 128 + c] = f2bf(acc);
    }
    if (chunk == 0 && t < 32) {
        int h2 = t >> 3, s2 = t & 7;
        float acc = 0.0f;
        for (int d2 = 0; d2 < 64; d2++)
            acc += bk[h2 * 64 + d2] * q_l[(s2 * 4 + h2) * 65 + d2];
        qb_ws[b * 32 + t] = acc;
    }
}

// ---------------- K2: MFMA scores + softmax + MFMA attF^T + MFMA epilogue --
__global__ __launch_bounds__(256, 4) void k_attn(
    const float* __restrict__ feat,   // (B,128,4096)
    const unsigned short* __restrict__ WvTH, const unsigned short* __restrict__ WvTl,
    const float* __restrict__ bv,
    const unsigned short* __restrict__ qkT, const float* __restrict__ qb_ws,
    float* __restrict__ agg_ws)
{
    __shared__ __align__(16) char smem[31360];
    unsigned short* featPC = (unsigned short*)smem;              // stride 136
    unsigned short* featCP = (unsigned short*)(smem + 8704);     // stride 56
    unsigned short* attFH  = (unsigned short*)smem;              // alias, stride 136
    unsigned short* attFL  = (unsigned short*)(smem + 8704);     // alias, stride 136
    float*          s_attn = (float*)(smem + 23040);             // stride 36
    unsigned short* s_aT   = (unsigned short*)(smem + 27648);    // stride 56
    float*          s_S    = (float*)(smem + 31232);

    int t = threadIdx.x, b = blockIdx.y, n0 = blockIdx.x * 128;
    int wv_ = t >> 6, lane = t & 63, quad = lane >> 4, l16 = lane & 15;
    int mt = wv_ >> 1, nt = wv_ & 1;
    int sp  = l16 + mt * 16;
    int shs = l16 + nt * 16;

    v8s bq_[4];
    #pragma unroll
    for (int ch = 0; ch < 4; ch++)
        bq_[ch] = *(const v8s*)&qkT[(b * 32 + shs) * 128 + ch * 32 + quad * 8];
    float qbv = qb_ws[b * 32 + shs];
    if (t < 32) s_S[t] = 0.0f;

    v4f accF[4];
    #pragma unroll
    for (int i = 0; i < 4; i++) accF[i] = (v4f){0.f, 0.f, 0.f, 0.f};

    int c0 = (t >> 3) * 4, p0 = (t & 7) * 4;

    for (int tt = 0; tt < 4; ++tt) {
        __syncthreads();
        int nb = n0 + tt * 32;
        float fv[4][4];
        #pragma unroll
        for (int r = 0; r < 4; r++) {
            float4 f = *(const float4*)&feat[(size_t)b * (FDIM * NPOS)
                                             + (size_t)(c0 + r) * NPOS + nb + p0];
            fv[r][0] = f.x; fv[r][1] = f.y; fv[r][2] = f.z; fv[r][3] = f.w;
        }
        #pragma unroll
        for (int r = 0; r < 4; r++)
            *(v4s*)&featCP[(c0 + r) * 56 + p0] =
                (v4s){(short)f2bf(fv[r][0]), (short)f2bf(fv[r][1]),
                      (short)f2bf(fv[r][2]), (short)f2bf(fv[r][3])};
        #pragma unroll
        for (int j = 0; j < 4; j++)
            *(v4s*)&featPC[(p0 + j) * 136 + c0] =
                (v4s){(short)f2bf(fv[0][j]), (short)f2bf(fv[1][j]),
                      (short)f2bf(fv[2][j]), (short)f2bf(fv[3][j])};
        __syncthreads();

        v4f acc = (v4f){0.f, 0.f, 0.f, 0.f};
        #pragma unroll
        for (int ch = 0; ch < 4; ch++) {
            v8s a = *(const v8s*)&featPC[sp * 136 + ch * 32 + quad * 8];
            acc = __builtin_amdgcn_mfma_f32_16x16x32_bf16(a, bq_[ch], acc, 0, 0, 0);
        }
        int pb = mt * 16 + quad * 4;
        #pragma unroll
        for (int r = 0; r < 4; r++)
            s_attn[(pb + r) * 36 + shs] = (acc[r] + qbv) * 0.125f;
        __syncthreads();

        if (t < 128) {
            int p = t >> 2, h2 = t & 3;
            float* a = &s_attn[p * 36 + h2 * 8];
            float m = a[0];
            for (int s = 1; s < 8; s++) m = fmaxf(m, a[s]);
            float e[8], ssum = 0.0f;
            for (int s = 0; s < 8; s++) { e[s] = __expf(a[s] - m); ssum += e[s]; }
            float inv = 1.0f / ssum;
            for (int s = 0; s < 8; s++)
                s_aT[(h2 * 8 + s) * 56 + p] = f2bf(e[s] * inv);
        }
        __syncthreads();

        v8s aA0 = *(const v8s*)&s_aT[l16 * 56 + quad * 8];
        v8s aA1 = *(const v8s*)&s_aT[(l16 + 16) * 56 + quad * 8];
        v8s bF0 = *(const v8s*)&featCP[(l16 + wv_ * 32) * 56 + quad * 8];
        v8s bF1 = *(const v8s*)&featCP[(l16 + wv_ * 32 + 16) * 56 + quad * 8];
        accF[0] = __builtin_amdgcn_mfma_f32_16x16x32_bf16(aA0, bF0, accF[0], 0, 0, 0);
        accF[1] = __builtin_amdgcn_mfma_f32_16x16x32_bf16(aA0, bF1, accF[1], 0, 0, 0);
        accF[2] = __builtin_amdgcn_mfma_f32_16x16x32_bf16(aA1, bF0, accF[2], 0, 0, 0);
        accF[3] = __builtin_amdgcn_mfma_f32_16x16x32_bf16(aA1, bF1, accF[3], 0, 0, 0);
        if (t < 32) {
            float ss = 0.0f;
            for (int p = 0; p < 32; p++) ss += bfr2f(s_aT[t * 56 + p]);
            s_S[t] += ss;
        }
    }
    __syncthreads();                 // feats views dead; alias as attFH/attFL
    #pragma unroll
    for (int mt2 = 0; mt2 < 2; mt2++)
        #pragma unroll
        for (int ntl = 0; ntl < 2; ntl++) {
            v4f f = accF[mt2 * 2 + ntl];
            int cc = wv_ * 32 + ntl * 16 + l16;
            #pragma unroll
            for (int r = 0; r < 4; r++) {
                unsigned short hi, lo; split2(f[r], hi, lo);
                attFH[(mt2 * 16 + quad * 4 + r) * 136 + cc] = hi;
                attFL[(mt2 * 16 + quad * 4 + r) * 136 + cc] = lo;
            }
        }
    __syncthreads();

    int h = wv_;
    int am = h * 8 + (l16 & 7);
    for (int nt2 = 0; nt2 < 4; nt2++) {
        int n = h * 64 + nt2 * 16 + l16;
        v4f acc = (v4f){0.f, 0.f, 0.f, 0.f};
        #pragma unroll
        for (int kk = 0; kk < 4; kk++) {
            int ko = kk * 32 + quad * 8;
            v8s ah = *(const v8s*)&attFH[am * 136 + ko];
            v8s al = *(const v8s*)&attFL[am * 136 + ko];
            v8s bh = *(const v8s*)&WvTH[(size_t)n * 128 + ko];
            v8s bl = *(const v8s*)&WvTl[(size_t)n * 128 + ko];
            acc = __builtin_amdgcn_mfma_f32_16x16x32_bf16(al, bh, acc, 0, 0, 0);
            acc = __builtin_amdgcn_mfma_f32_16x16x32_bf16(ah, bl, acc, 0, 0, 0);
            acc = __builtin_amdgcn_mfma_f32_16x16x32_bf16(ah, bh, acc, 0, 0, 0);
        }
        float bvn = bv[n];
        if (quad < 2) {
            #pragma unroll
            for (int r = 0; r < 4; r++) {
                int s = quad * 4 + r;
                atomicAdd(&agg_ws[b * 2048 + s * 256 + n],
                          acc[r] + s_S[h * 8 + s] * bvn);
            }
        }
    }
}

__device__ __forceinline__ float gru1(float ir, float iz, float in_,
                                      float hr, float hz, float hn, float hp) {
    float r = 1.0f / (1.0f + __expf(-(ir + hr)));
    float z = 1.0f / (1.0f + __expf(-(iz + hz)));
    float n = tanhf(in_ + r * hn);
    return (1.0f - z) * n + z * hp;
}

// ---------------- K3 (COOPERATIVE, 256 blocks x 256 thr = 1024 waves):
// phase 1: G[256][1536] gate GEMM (1536 wave-tiles of 16x16, split-bf16 MFMA)
// phase 2: GRU elementwise + post-LN (256 wave-rows) -> lnH/lnLo, hnF
// phase 3: y1[256][512] = relu(ln@W1+b1) (512 wave-tiles) -> y1H/y1Lo
// phase 4: out[256][256] = hn + y1@W2 + b2 (256 wave-tiles)
// grid.sync() between phases. No LDS -> full co-residency.
__global__ __launch_bounds__(256) void k_tail(
    const float* __restrict__ slots, const float* __restrict__ agg,
    float* __restrict__ G,
    const unsigned short* __restrict__ WihH, const unsigned short* __restrict__ WihL,
    const float* __restrict__ b_ih,
    const unsigned short* __restrict__ WhhH, const unsigned short* __restrict__ WhhL,
    const float* __restrict__ b_hh,
    const float* __restrict__ g_post, const float* __restrict__ b_post,
    const unsigned short* __restrict__ W1Th, const unsigned short* __restrict__ W1Tl,
    const float* __restrict__ b1,
    const unsigned short* __restrict__ W2Th, const unsigned short* __restrict__ W2Tl,
    const float* __restrict__ b2,
    unsigned short* __restrict__ lnH, unsigned short* __restrict__ lnLo,
    float* __restrict__ hnF,
    unsigned short* __restrict__ y1H, unsigned short* __restrict__ y1Lo,
    float* __restrict__ out)
{
    cg::grid_group grid = cg::this_grid();
    int t = threadIdx.x;
    int lane = t & 63, quad = lane >> 4, l16 = lane & 15;
    int gw = blockIdx.x * 4 + (t >> 6);      // global wave id, 0..1023

    // ---- phase 1: gate GEMM; tile tid: mt = tid/96, ntile = tid%96 ----
    for (int tid = gw; tid < 1536; tid += 1024) {
        int mt = tid / 96, ntile = tid % 96;
        bool hh = ntile >= 48;
        int jbase = (ntile - (hh ? 48 : 0)) * 16;
        const float* X = hh ? slots : agg;
        const unsigned short* BH = hh ? WhhH : WihH;
        const unsigned short* BL = hh ? WhhL : WihL;
        const float* bias = hh ? b_hh : b_ih;
        int gofs = hh ? 768 : 0;
        int arow = mt * 16 + l16;
        int jrow = jbase + l16;
        v4f acc = (v4f){0.f, 0.f, 0.f, 0.f};
        #pragma unroll
        for (int kk = 0; kk < 8; kk++) {
            int ko = kk * 32 + quad * 8;
            float4 x0 = *(const float4*)&X[(size_t)arow * 256 + ko];
            float4 x1 = *(const float4*)&X[(size_t)arow * 256 + ko + 4];
            unsigned short h_[8], l_[8];
            split2(x0.x, h_[0], l_[0]); split2(x0.y, h_[1], l_[1]);
            split2(x0.z, h_[2], l_[2]); split2(x0.w, h_[3], l_[3]);
            split2(x1.x, h_[4], l_[4]); split2(x1.y, h_[5], l_[5]);
            split2(x1.z, h_[6], l_[6]); split2(x1.w, h_[7], l_[7]);
            v8s ah = (v8s){(short)h_[0],(short)h_[1],(short)h_[2],(short)h_[3],
                           (short)h_[4],(short)h_[5],(short)h_[6],(short)h_[7]};
            v8s al = (v8s){(short)l_[0],(short)l_[1],(short)l_[2],(short)l_[3],
                           (short)l_[4],(short)l_[5],(short)l_[6],(short)l_[7]};
            v8s bh = *(const v8s*)&BH[(size_t)jrow * 256 + ko];
            v8s bl = *(const v8s*)&BL[(size_t)jrow * 256 + ko];
            acc = __builtin_amdgcn_mfma_f32_16x16x32_bf16(al, bh, acc, 0, 0, 0);
            acc = __builtin_amdgcn_mfma_f32_16x16x32_bf16(ah, bl, acc, 0, 0, 0);
            acc = __builtin_amdgcn_mfma_f32_16x16x32_bf16(ah, bh, acc, 0, 0, 0);
        }
        float bb = bias[jbase + l16];
        #pragma unroll
        for (int r = 0; r < 4; r++)
            G[(size_t)(mt * 16 + quad * 4 + r) * 1536 + gofs + jbase + l16] = acc[r] + bb;
    }
    __threadfence();
    grid.sync();

    // ---- phase 2: GRU + LN, one wave per row ----
    if (gw < 256) {
        int row = gw;
        int c0 = lane * 4;
        const float* gp = &G[(size_t)row * 1536 + c0];
        float4 gir = *(const float4*)(gp);
        float4 giz = *(const float4*)(gp + 256);
        float4 gin = *(const float4*)(gp + 512);
        float4 ghr = *(const float4*)(gp + 768);
        float4 ghz = *(const float4*)(gp + 1024);
        float4 ghn = *(const float4*)(gp + 1280);
        float4 hp  = *(const float4*)&slots[(size_t)row * 256 + c0];
        float h0 = gru1(gir.x, giz.x, gin.x, ghr.x, ghz.x, ghn.x, hp.x);
        float h1 = gru1(gir.y, giz.y, gin.y, ghr.y, ghz.y, ghn.y, hp.y);
        float h2 = gru1(gir.z, giz.z, gin.z, ghr.z, ghz.z, ghn.z, hp.z);
        float h3 = gru1(gir.w, giz.w, gin.w, ghr.w, ghz.w, ghn.w, hp.w);
        float ssum = h0 + h1 + h2 + h3;
        float ssq  = h0*h0 + h1*h1 + h2*h2 + h3*h3;
        #pragma unroll
        for (int m = 1; m <= 32; m <<= 1) {
            ssum += __shfl_xor(ssum, m, 64);
            ssq  += __shfl_xor(ssq, m, 64);
        }
        float mu = ssum * (1.0f / 256);
        float var = ssq * (1.0f / 256) - mu * mu;
        float rstd = rsqrtf(var + 1e-5f);
        float4 gp4 = *(const float4*)&g_post[c0];
        float4 bp4 = *(const float4*)&b_post[c0];
        float l0 = (h0 - mu) * rstd * gp4.x + bp4.x;
        float l1 = (h1 - mu) * rstd * gp4.y + bp4.y;
        float l2 = (h2 - mu) * rstd * gp4.z + bp4.z;
        float l3 = (h3 - mu) * rstd * gp4.w + bp4.w;
        unsigned short a0,b0,a1,b1_,a2,b2_,a3,b3;
        split2(l0, a0, b0); split2(l1, a1, b1_);
        split2(l2, a2, b2_); split2(l3, a3, b3);
        *(v4s*)&lnH[(size_t)row * 256 + c0]  = (v4s){(short)a0,(short)a1,(short)a2,(short)a3};
        *(v4s*)&lnLo[(size_t)row * 256 + c0] = (v4s){(short)b0,(short)b1_,(short)b2_,(short)b3};
        float4 hv4; hv4.x = h0; hv4.y = h1; hv4.z = h2; hv4.w = h3;
        *(float4*)&hnF[(size_t)row * 256 + c0] = hv4;
    }
    __threadfence();
    grid.sync();

    // ---- phase 3: MLP1, tile gw: mt = gw>>5, ntile = gw&31 ----
    if (gw < 512) {
        int mt = gw >> 5, ntile = gw & 31;
        int n = ntile * 16 + l16;
        v4f acc = (v4f){0.f, 0.f, 0.f, 0.f};
        #pragma unroll
        for (int kk = 0; kk < 8; kk++) {
            int ko = kk * 32 + quad * 8;
            v8s ah = *(const v8s*)&lnH[(size_t)(mt * 16 + l16) * 256 + ko];
            v8s al = *(const v8s*)&lnLo[(size_t)(mt * 16 + l16) * 256 + ko];
            v8s bh = *(const v8s*)&W1Th[(size_t)n * 256 + ko];
            v8s bl = *(const v8s*)&W1Tl[(size_t)n * 256 + ko];
            acc = __builtin_amdgcn_mfma_f32_16x16x32_bf16(al, bh, acc, 0, 0, 0);
            acc = __builtin_amdgcn_mfma_f32_16x16x32_bf16(ah, bl, acc, 0, 0, 0);
            acc = __builtin_amdgcn_mfma_f32_16x16x32_bf16(ah, bh, acc, 0, 0, 0);
        }
        float bb = b1[n];
        #pragma unroll
        for (int r = 0; r < 4; r++) {
            float y = fmaxf(acc[r] + bb, 0.0f);
            unsigned short hi, lo; split2(y, hi, lo);
            y1H[(size_t)(mt * 16 + quad * 4 + r) * 512 + n]  = hi;
            y1Lo[(size_t)(mt * 16 + quad * 4 + r) * 512 + n] = lo;
        }
    }
    __threadfence();
    grid.sync();

    // ---- phase 4: MLP2 + residual, tile gw: mt = gw>>4, ntile = gw&15 ----
    if (gw < 256) {
        int mt = gw >> 4, ntile = gw & 15;
        int n = ntile * 16 + l16;
        v4f acc = (v4f){0.f, 0.f, 0.f, 0.f};
        #pragma unroll
        for (int kk = 0; kk < 16; kk++) {
            int ko = kk * 32 + quad * 8;
            v8s ah = *(const v8s*)&y1H[(size_t)(mt * 16 + l16) * 512 + ko];
            v8s al = *(const v8s*)&y1Lo[(size_t)(mt * 16 + l16) * 512 + ko];
            v8s bh = *(const v8s*)&W2Th[(size_t)n * 512 + ko];
            v8s bl = *(const v8s*)&W2Tl[(size_t)n * 512 + ko];
            acc = __builtin_amdgcn_mfma_f32_16x16x32_bf16(al, bh, acc, 0, 0, 0);
            acc = __builtin_amdgcn_mfma_f32_16x16x32_bf16(ah, bl, acc, 0, 0, 0);
            acc = __builtin_amdgcn_mfma_f32_16x16x32_bf16(ah, bh, acc, 0, 0, 0);
        }
        float bb = b2[n];
        #pragma unroll
        for (int r = 0; r < 4; r++) {
            int m = mt * 16 + quad * 4 + r;
            out[(size_t)m * 256 + n] = hnF[(size_t)m * 256 + n] + acc[r] + bb;
        }
    }
}

extern "C" void kernel_launch(void* const* d_in, const int* in_sizes, int n_in,
                              void* d_out, int out_size, void* d_ws, size_t ws_size,
                              hipStream_t stream) {
    const float* features = (const float*)d_in[0];
    const float* slots    = (const float*)d_in[1];
    const float* Wq   = (const float*)d_in[2];
    const float* bq   = (const float*)d_in[3];
    const float* Wk   = (const float*)d_in[4];
    const float* bk   = (const float*)d_in[5];
    const float* Wv   = (const float*)d_in[6];
    const float* bv   = (const float*)d_in[7];
    const float* W_ih = (const float*)d_in[8];
    const float* b_ih = (const float*)d_in[9];
    const float* W_hh = (const float*)d_in[10];
    const float* b_hh = (const float*)d_in[11];
    const float* g_pre  = (const float*)d_in[12];
    const float* b_pre  = (const float*)d_in[13];
    const float* g_post = (const float*)d_in[14];
    const float* b_post = (const float*)d_in[15];
    const float* W1 = (const float*)d_in[16];
    const float* b1 = (const float*)d_in[17];
    const float* W2 = (const float*)d_in[18];
    const float* b2 = (const float*)d_in[19];
    float* out = (float*)d_out;

    char* wsb = (char*)d_ws;
    float* G               = (float*)wsb;
    unsigned short* qkT_ws = (unsigned short*)wsb;              // aliases G (dead after k_attn)
    float* qb_ws           = (float*)(wsb + 262144);
    unsigned short* W1Th   = (unsigned short*)(wsb + 1572864);
    unsigned short* W1Tl   = (unsigned short*)(wsb + 1835008);
    unsigned short* W2Th   = (unsigned short*)(wsb + 2097152);
    unsigned short* W2Tl   = (unsigned short*)(wsb + 2359296);
    unsigned short* WihH   = (unsigned short*)(wsb + 2621440);
    unsigned short* WihL   = (unsigned short*)(wsb + 3014656);
    unsigned short* WhhH   = (unsigned short*)(wsb + 3407872);
    unsigned short* WhhL   = (unsigned short*)(wsb + 3801088);
    unsigned short* WvTH   = (unsigned short*)(wsb + 4194304);
    unsigned short* WvTl   = (unsigned short*)(wsb + 4259840);
    unsigned short* lnH    = (unsigned short*)(wsb + 4325376);
    unsigned short* lnLo   = (unsigned short*)(wsb + 4456448);
    float* hnF             = (float*)(wsb + 4587520);
    unsigned short* y1H    = (unsigned short*)(wsb + 4849664);
    unsigned short* y1Lo   = (unsigned short*)(wsb + 5111808);
    float* agg_ws = out;   // agg accumulator in d_out (zeroed by K1 chunk0)

    k_prep<<<dim3(592), dim3(256), 0, stream>>>(
        slots, Wq, bq, g_pre, b_pre, Wk, bk, W1, W2, W_ih, W_hh, Wv,
        qkT_ws, qb_ws, W1Th, W1Tl, W2Th, W2Tl,
        WihH, WihL, WhhH, WhhL, WvTH, WvTl, agg_ws);
    k_attn<<<dim3(32, 32), dim3(256), 0, stream>>>(
        features, WvTH, WvTl, bv, qkT_ws, qb_ws, agg_ws);

    const float* aggc = (const float*)out;
    void* args[] = {
        (void*)&slots, (void*)&aggc, (void*)&G,
        (void*)&WihH, (void*)&WihL, (void*)&b_ih,
        (void*)&WhhH, (void*)&WhhL, (void*)&b_hh,
        (void*)&g_post, (void*)&b_post,
        (void*)&W1Th, (void*)&W1Tl, (void*)&b1,
        (void*)&W2Th, (void*)&W2Tl, (void*)&b2,
        (void*)&lnH, (void*)&lnLo, (void*)&hnF,
        (void*)&y1H, (void*)&y1Lo, (void*)&out
    };
    hipLaunchCooperativeKernel((void*)k_tail, dim3(256), dim3(256), args, 0, stream);
}

// Round 16
// 241.355 us; speedup vs baseline: 1.5345x; 1.5345x over previous
//
#include <hip/hip_runtime.h>
#include <hip/hip_bf16.h>

#define NSLOT 8
#define SDIM 256
#define FDIM 128
#define NHEAD 4
#define HDIM 64
#define NPOS 4096

typedef short v8s __attribute__((ext_vector_type(8)));
typedef short v4s __attribute__((ext_vector_type(4)));
typedef float v4f __attribute__((ext_vector_type(4)));

__device__ __forceinline__ unsigned short f2bf(float x) {
    __hip_bfloat16 h = __float2bfloat16(x);
    unsigned short u; __builtin_memcpy(&u, &h, 2); return u;
}
__device__ __forceinline__ float bfr2f(unsigned short u) {
    __hip_bfloat16 h; __builtin_memcpy(&h, &u, 2); return __bfloat162float(h);
}
__device__ __forceinline__ void splitf(float x, unsigned short& hi, unsigned short& lo) {
    hi = f2bf(x);
    lo = f2bf(x - bfr2f(hi));
}

// ---------------- K1 (fused prep, 544 blocks):
//   blk   0..255: per-batch LN(slots)+q+qkT/qb, zero agg (b=blk>>3, chunk=blk&7)
//   blk 256..511: W1 (256x512) / W2 (512x256) transpose -> hi/lo bf16 [n][k]
//   blk 512..543: Wv (128x256) transpose -> WvT hi/lo bf16 [256][128]
__global__ __launch_bounds__(256) void k_prep(
    const float* __restrict__ slots,
    const float* __restrict__ Wq, const float* __restrict__ bq,
    const float* __restrict__ g_pre, const float* __restrict__ b_pre,
    const float* __restrict__ Wk, const float* __restrict__ bk,
    const float* __restrict__ W1, const float* __restrict__ W2,
    const float* __restrict__ Wv,
    unsigned short* __restrict__ qkT_ws, float* __restrict__ qb_ws,
    unsigned short* __restrict__ W1Th, unsigned short* __restrict__ W1Tl,
    unsigned short* __restrict__ W2Th, unsigned short* __restrict__ W2Tl,
    unsigned short* __restrict__ WvTH, unsigned short* __restrict__ WvTl,
    float* __restrict__ agg_ws)
{
    int blk = blockIdx.x, t = threadIdx.x;
    __shared__ float s_ln[8 * 256];
    __shared__ float q_l[32 * 65];
    __shared__ float red1[256], red2[256];
    __shared__ float tl[32][33];

    if (blk >= 512) {                // WvT transpose+split (32 blocks)
        int id3 = blk - 512;
        int k0 = (id3 & 3) * 32, n0 = (id3 >> 2) * 32;
        for (int i = 0; i < 4; i++) {
            int idx = i * 256 + t, r = idx >> 5, c = idx & 31;
            tl[r][c] = Wv[(size_t)(k0 + r) * 256 + n0 + c];
        }
        __syncthreads();
        for (int i = 0; i < 4; i++) {
            int idx = i * 256 + t, r = idx >> 5, c = idx & 31;
            unsigned short hi, lo; splitf(tl[c][r], hi, lo);
            WvTH[(size_t)(n0 + r) * 128 + k0 + c] = hi;
            WvTl[(size_t)(n0 + r) * 128 + k0 + c] = lo;
        }
        return;
    }
    if (blk >= 256) {                // W1/W2 transpose+split
        int id = blk - 256;
        const float* src; unsigned short *dh, *dl; int N, K, k0, n0;
        if (id < 128) { src = W1; dh = W1Th; dl = W1Tl; N = 512; K = 256;
                        k0 = (id >> 4) * 32; n0 = (id & 15) * 32; }
        else          { int i2 = id - 128; src = W2; dh = W2Th; dl = W2Tl; N = 256; K = 512;
                        k0 = (i2 >> 3) * 32; n0 = (i2 & 7) * 32; }
        for (int i = 0; i < 4; i++) {
            int idx = i * 256 + t, r = idx >> 5, c = idx & 31;
            tl[r][c] = src[(size_t)(k0 + r) * N + n0 + c];
        }
        __syncthreads();
        for (int i = 0; i < 4; i++) {
            int idx = i * 256 + t, r = idx >> 5, c = idx & 31;
            unsigned short hi, lo; splitf(tl[c][r], hi, lo);
            dh[(size_t)(n0 + r) * K + k0 + c] = hi;
            dl[(size_t)(n0 + r) * K + k0 + c] = lo;
        }
        return;
    }

    // ---- per-batch prep ----
    int b = blk >> 3, chunk = blk & 7;
    if (chunk == 0)
        for (int i = 0; i < 8; i++) agg_ws[b * 2048 + i * 256 + t] = 0.0f;

    int s8 = t >> 5, lane = t & 31;
    float xv[8], sum = 0.0f, sq = 0.0f;
    for (int u = 0; u < 8; u++) {
        float x = slots[(b * 8 + s8) * 256 + lane * 8 + u];
        xv[u] = x; sum += x; sq += x * x;
    }
    red1[t] = sum; red2[t] = sq;
    __syncthreads();
    for (int o = 16; o > 0; o >>= 1) {
        if (lane < o) { red1[t] += red1[t + o]; red2[t] += red2[t + o]; }
        __syncthreads();
    }
    float mu  = red1[s8 * 32] * (1.0f / 256);
    float var = red2[s8 * 32] * (1.0f / 256) - mu * mu;
    float rstd = rsqrtf(var + 1e-5f);
    for (int u = 0; u < 8; u++) {
        int j = lane * 8 + u;
        s_ln[s8 * 256 + j] = (xv[u] - mu) * rstd * g_pre[j] + b_pre[j];
    }
    __syncthreads();

    float qa[8];
    #pragma unroll
    for (int s = 0; s < 8; s++) qa[s] = bq[t];
    for (int k = 0; k < 256; k++) {
        float wq = Wq[k * 256 + t];
        #pragma unroll
        for (int s = 0; s < 8; s++) qa[s] += s_ln[s * 256 + k] * wq;
    }
    int h = t >> 6, d = t & 63;
    for (int s = 0; s < 8; s++) q_l[(s * 4 + h) * 65 + d] = qa[s];
    __syncthreads();

    int hs = t & 31, hh = hs >> 3, si = hs & 7, c0 = t >> 5;
    const float* qrow = &q_l[(si * 4 + hh) * 65];
    for (int i = 0; i < 2; i++) {
        int c = chunk * 16 + i * 8 + c0;
        const float4* wk4 = (const float4*)&Wk[c * 256 + hh * 64];
        float acc = 0.0f;
        #pragma unroll
        for (int d4 = 0; d4 < 16; d4++) {
            float4 w = wk4[d4];
            acc += w.x * qrow[d4 * 4] + w.y * qrow[d4 * 4 + 1]
                 + w.z * qrow[d4 * 4 + 2] + w.w * qrow[d4 * 4 + 3];
        }
        qkT_ws[(b * 32 + hs) * 128 + c] = f2bf(acc);
    }
    if (chunk == 0 && t < 32) {
        int h2 = t >> 3, s2 = t & 7;
        float acc = 0.0f;
        for (int d2 = 0; d2 < 64; d2++)
            acc += bk[h2 * 64 + d2] * q_l[(s2 * 4 + h2) * 65 + d2];
        qb_ws[b * 32 + t] = acc;
    }
}

// ---------------- K2: MFMA scores + softmax + MFMA attF^T + MFMA epilogue --
__global__ __launch_bounds__(256, 4) void k_attn(
    const float* __restrict__ feat,   // (B,128,4096)
    const unsigned short* __restrict__ WvTH, const unsigned short* __restrict__ WvTl,
    const float* __restrict__ bv,
    const unsigned short* __restrict__ qkT, const float* __restrict__ qb_ws,
    float* __restrict__ agg_ws)
{
    __shared__ __align__(16) char smem[31360];
    unsigned short* featPC = (unsigned short*)smem;              // stride 136
    unsigned short* featCP = (unsigned short*)(smem + 8704);     // stride 56
    unsigned short* attFH  = (unsigned short*)smem;              // alias, stride 136
    unsigned short* attFL  = (unsigned short*)(smem + 8704);     // alias, stride 136
    float*          s_attn = (float*)(smem + 23040);             // stride 36
    unsigned short* s_aT   = (unsigned short*)(smem + 27648);    // stride 56
    float*          s_S    = (float*)(smem + 31232);

    int t = threadIdx.x, b = blockIdx.y, n0 = blockIdx.x * 128;
    int wv_ = t >> 6, lane = t & 63, quad = lane >> 4, l16 = lane & 15;
    int mt = wv_ >> 1, nt = wv_ & 1;
    int sp  = l16 + mt * 16;
    int shs = l16 + nt * 16;

    v8s bq_[4];
    #pragma unroll
    for (int ch = 0; ch < 4; ch++)
        bq_[ch] = *(const v8s*)&qkT[(b * 32 + shs) * 128 + ch * 32 + quad * 8];
    float qbv = qb_ws[b * 32 + shs];
    if (t < 32) s_S[t] = 0.0f;

    v4f accF[4];
    #pragma unroll
    for (int i = 0; i < 4; i++) accF[i] = (v4f){0.f, 0.f, 0.f, 0.f};

    int c0 = (t >> 3) * 4, p0 = (t & 7) * 4;

    for (int tt = 0; tt < 4; ++tt) {
        __syncthreads();
        int nb = n0 + tt * 32;
        float fv[4][4];
        #pragma unroll
        for (int r = 0; r < 4; r++) {
            float4 f = *(const float4*)&feat[(size_t)b * (FDIM * NPOS)
                                             + (size_t)(c0 + r) * NPOS + nb + p0];
            fv[r][0] = f.x; fv[r][1] = f.y; fv[r][2] = f.z; fv[r][3] = f.w;
        }
        #pragma unroll
        for (int r = 0; r < 4; r++)
            *(v4s*)&featCP[(c0 + r) * 56 + p0] =
                (v4s){(short)f2bf(fv[r][0]), (short)f2bf(fv[r][1]),
                      (short)f2bf(fv[r][2]), (short)f2bf(fv[r][3])};
        #pragma unroll
        for (int j = 0; j < 4; j++)
            *(v4s*)&featPC[(p0 + j) * 136 + c0] =
                (v4s){(short)f2bf(fv[0][j]), (short)f2bf(fv[1][j]),
                      (short)f2bf(fv[2][j]), (short)f2bf(fv[3][j])};
        __syncthreads();

        v4f acc = (v4f){0.f, 0.f, 0.f, 0.f};
        #pragma unroll
        for (int ch = 0; ch < 4; ch++) {
            v8s a = *(const v8s*)&featPC[sp * 136 + ch * 32 + quad * 8];
            acc = __builtin_amdgcn_mfma_f32_16x16x32_bf16(a, bq_[ch], acc, 0, 0, 0);
        }
        int pb = mt * 16 + quad * 4;
        #pragma unroll
        for (int r = 0; r < 4; r++)
            s_attn[(pb + r) * 36 + shs] = (acc[r] + qbv) * 0.125f;
        __syncthreads();

        if (t < 128) {
            int p = t >> 2, h2 = t & 3;
            float* a = &s_attn[p * 36 + h2 * 8];
            float m = a[0];
            for (int s = 1; s < 8; s++) m = fmaxf(m, a[s]);
            float e[8], ssum = 0.0f;
            for (int s = 0; s < 8; s++) { e[s] = __expf(a[s] - m); ssum += e[s]; }
            float inv = 1.0f / ssum;
            for (int s = 0; s < 8; s++)
                s_aT[(h2 * 8 + s) * 56 + p] = f2bf(e[s] * inv);
        }
        __syncthreads();

        v8s aA0 = *(const v8s*)&s_aT[l16 * 56 + quad * 8];
        v8s aA1 = *(const v8s*)&s_aT[(l16 + 16) * 56 + quad * 8];
        v8s bF0 = *(const v8s*)&featCP[(l16 + wv_ * 32) * 56 + quad * 8];
        v8s bF1 = *(const v8s*)&featCP[(l16 + wv_ * 32 + 16) * 56 + quad * 8];
        accF[0] = __builtin_amdgcn_mfma_f32_16x16x32_bf16(aA0, bF0, accF[0], 0, 0, 0);
        accF[1] = __builtin_amdgcn_mfma_f32_16x16x32_bf16(aA0, bF1, accF[1], 0, 0, 0);
        accF[2] = __builtin_amdgcn_mfma_f32_16x16x32_bf16(aA1, bF0, accF[2], 0, 0, 0);
        accF[3] = __builtin_amdgcn_mfma_f32_16x16x32_bf16(aA1, bF1, accF[3], 0, 0, 0);
        if (t < 32) {
            float ss = 0.0f;
            for (int p = 0; p < 32; p++) ss += bfr2f(s_aT[t * 56 + p]);
            s_S[t] += ss;
        }
    }
    __syncthreads();                 // feats views dead; alias as attFH/attFL
    #pragma unroll
    for (int mt2 = 0; mt2 < 2; mt2++)
        #pragma unroll
        for (int ntl = 0; ntl < 2; ntl++) {
            v4f f = accF[mt2 * 2 + ntl];
            int cc = wv_ * 32 + ntl * 16 + l16;
            #pragma unroll
            for (int r = 0; r < 4; r++) {
                unsigned short hi, lo; splitf(f[r], hi, lo);
                attFH[(mt2 * 16 + quad * 4 + r) * 136 + cc] = hi;
                attFL[(mt2 * 16 + quad * 4 + r) * 136 + cc] = lo;
            }
        }
    __syncthreads();

    int h = wv_;
    int am = h * 8 + (l16 & 7);
    for (int nt2 = 0; nt2 < 4; nt2++) {
        int n = h * 64 + nt2 * 16 + l16;
        v4f acc = (v4f){0.f, 0.f, 0.f, 0.f};
        #pragma unroll
        for (int kk = 0; kk < 4; kk++) {
            int ko = kk * 32 + quad * 8;
            v8s ah = *(const v8s*)&attFH[am * 136 + ko];
            v8s al = *(const v8s*)&attFL[am * 136 + ko];
            v8s bh = *(const v8s*)&WvTH[(size_t)n * 128 + ko];
            v8s bl = *(const v8s*)&WvTl[(size_t)n * 128 + ko];
            acc = __builtin_amdgcn_mfma_f32_16x16x32_bf16(al, bh, acc, 0, 0, 0);
            acc = __builtin_amdgcn_mfma_f32_16x16x32_bf16(ah, bl, acc, 0, 0, 0);
            acc = __builtin_amdgcn_mfma_f32_16x16x32_bf16(ah, bh, acc, 0, 0, 0);
        }
        float bvn = bv[n];
        if (quad < 2) {
            #pragma unroll
            for (int r = 0; r < 4; r++) {
                int s = quad * 4 + r;
                atomicAdd(&agg_ws[b * 2048 + s * 256 + n],
                          acc[r] + s_S[h * 8 + s] * bvn);
            }
        }
    }
}

__device__ __forceinline__ float gru1(float ir, float iz, float in_,
                                      float hr, float hz, float hn, float hp) {
    float r = 1.0f / (1.0f + __expf(-(ir + hr)));
    float z = 1.0f / (1.0f + __expf(-(iz + hz)));
    float n = tanhf(in_ + r * hn);
    return (1.0f - z) * n + z * hp;
}

// ---------------- K3: ROW-LOCAL TAIL — one ORDINARY kernel, 16 blocks x 1024
// threads (16 waves). Phases separated by __syncthreads only (all deps are
// within the block's 16 rows):
//   A: gate GEMM G[16rows][1536] (96 wave-tiles, 6/wave; B split in-flight)
//   B: GRU + post-LN (1 row/wave) -> ln hi/lo (LDS), hn (global hnF)
//   C: MLP1 y1 = relu(ln@W1+b1) (32 tiles, 2/wave) -> y1 hi/lo (LDS)
//   D: MLP2 out = hn + y1@W2+b2 (16 tiles, 1/wave)
__global__ __launch_bounds__(1024) void k_tail(
    const float* __restrict__ slots, const float* __restrict__ agg,
    const float* __restrict__ W_ih, const float* __restrict__ b_ih,
    const float* __restrict__ W_hh, const float* __restrict__ b_hh,
    const float* __restrict__ g_post, const float* __restrict__ b_post,
    const unsigned short* __restrict__ W1Th, const unsigned short* __restrict__ W1Tl,
    const float* __restrict__ b1,
    const unsigned short* __restrict__ W2Th, const unsigned short* __restrict__ W2Tl,
    const float* __restrict__ b2,
    float* __restrict__ G, float* __restrict__ hnF, float* __restrict__ out)
{
    __shared__ __align__(16) char smem[50176];
    // phase A views ([16][264] bf16 = 8448 B each):
    unsigned short* aggH  = (unsigned short*)smem;
    unsigned short* aggL  = (unsigned short*)(smem + 8448);
    unsigned short* slotH = (unsigned short*)(smem + 16896);
    unsigned short* slotL = (unsigned short*)(smem + 25344);
    // phase B/C/D views (alias; safe — phase A consumers done before writes):
    unsigned short* lnH   = (unsigned short*)smem;               // [16][264]
    unsigned short* lnLo  = (unsigned short*)(smem + 8448);
    unsigned short* y1H   = (unsigned short*)(smem + 16896);     // [16][520]
    unsigned short* y1Lo  = (unsigned short*)(smem + 33536);     // 16640 B each

    int t = threadIdx.x, m0 = blockIdx.x * 16;
    int w = t >> 6, lane = t & 63, quad = lane >> 4, l16 = lane & 15;

    // stage A rows (agg & slots) hi/lo into LDS: thread -> (row, 4 cols)
    {
        int r = t >> 6, c = (t & 63) * 4;
        float4 fa = *(const float4*)&agg[(size_t)(m0 + r) * 256 + c];
        float4 fs = *(const float4*)&slots[(size_t)(m0 + r) * 256 + c];
        unsigned short h0,l0,h1,l1,h2,l2,h3,l3;
        splitf(fa.x,h0,l0); splitf(fa.y,h1,l1); splitf(fa.z,h2,l2); splitf(fa.w,h3,l3);
        *(v4s*)&aggH[r * 264 + c] = (v4s){(short)h0,(short)h1,(short)h2,(short)h3};
        *(v4s*)&aggL[r * 264 + c] = (v4s){(short)l0,(short)l1,(short)l2,(short)l3};
        splitf(fs.x,h0,l0); splitf(fs.y,h1,l1); splitf(fs.z,h2,l2); splitf(fs.w,h3,l3);
        *(v4s*)&slotH[r * 264 + c] = (v4s){(short)h0,(short)h1,(short)h2,(short)h3};
        *(v4s*)&slotL[r * 264 + c] = (v4s){(short)l0,(short)l1,(short)l2,(short)l3};
    }
    __syncthreads();

    // ---- phase A: gate GEMM (96 tiles / 16 waves = 6 each) ----
    #pragma unroll
    for (int i = 0; i < 6; i++) {
        int ntile = w + 16 * i;                  // 0..95
        bool hh = ntile >= 48;
        int jbase = (ntile - (hh ? 48 : 0)) * 16;
        const unsigned short* AH = hh ? slotH : aggH;
        const unsigned short* AL = hh ? slotL : aggL;
        const float* W = hh ? W_hh : W_ih;
        const float* bias = hh ? b_hh : b_ih;
        int gofs = hh ? 768 : 0;
        int jrow = jbase + l16;
        v4f acc = (v4f){0.f, 0.f, 0.f, 0.f};
        #pragma unroll
        for (int kk = 0; kk < 8; kk++) {
            int ko = kk * 32 + quad * 8;
            v8s ah = *(const v8s*)&AH[l16 * 264 + ko];
            v8s al = *(const v8s*)&AL[l16 * 264 + ko];
            float4 w0 = *(const float4*)&W[(size_t)jrow * 256 + ko];
            float4 w1 = *(const float4*)&W[(size_t)jrow * 256 + ko + 4];
            unsigned short bh_[8], bl_[8];
            splitf(w0.x, bh_[0], bl_[0]); splitf(w0.y, bh_[1], bl_[1]);
            splitf(w0.z, bh_[2], bl_[2]); splitf(w0.w, bh_[3], bl_[3]);
            splitf(w1.x, bh_[4], bl_[4]); splitf(w1.y, bh_[5], bl_[5]);
            splitf(w1.z, bh_[6], bl_[6]); splitf(w1.w, bh_[7], bl_[7]);
            v8s bh = (v8s){(short)bh_[0],(short)bh_[1],(short)bh_[2],(short)bh_[3],
                           (short)bh_[4],(short)bh_[5],(short)bh_[6],(short)bh_[7]};
            v8s bl = (v8s){(short)bl_[0],(short)bl_[1],(short)bl_[2],(short)bl_[3],
                           (short)bl_[4],(short)bl_[5],(short)bl_[6],(short)bl_[7]};
            acc = __builtin_amdgcn_mfma_f32_16x16x32_bf16(al, bh, acc, 0, 0, 0);
            acc = __builtin_amdgcn_mfma_f32_16x16x32_bf16(ah, bl, acc, 0, 0, 0);
            acc = __builtin_amdgcn_mfma_f32_16x16x32_bf16(ah, bh, acc, 0, 0, 0);
        }
        float bb = bias[jrow];
        #pragma unroll
        for (int r = 0; r < 4; r++)
            G[(size_t)(m0 + quad * 4 + r) * 1536 + gofs + jbase + l16] = acc[r] + bb;
    }
    __syncthreads();   // G visible block-wide (same CU; barrier drains vmcnt)

    // ---- phase B: GRU + LN, wave w -> row m0 + w ----
    {
        int row = m0 + w, c0 = lane * 4;
        const float* gp = &G[(size_t)row * 1536 + c0];
        float4 gir = *(const float4*)(gp);
        float4 giz = *(const float4*)(gp + 256);
        float4 gin = *(const float4*)(gp + 512);
        float4 ghr = *(const float4*)(gp + 768);
        float4 ghz = *(const float4*)(gp + 1024);
        float4 ghn = *(const float4*)(gp + 1280);
        float4 hp  = *(const float4*)&slots[(size_t)row * 256 + c0];
        float h0 = gru1(gir.x, giz.x, gin.x, ghr.x, ghz.x, ghn.x, hp.x);
        float h1 = gru1(gir.y, giz.y, gin.y, ghr.y, ghz.y, ghn.y, hp.y);
        float h2 = gru1(gir.z, giz.z, gin.z, ghr.z, ghz.z, ghn.z, hp.z);
        float h3 = gru1(gir.w, giz.w, gin.w, ghr.w, ghz.w, ghn.w, hp.w);
        float ssum = h0 + h1 + h2 + h3;
        float ssq  = h0*h0 + h1*h1 + h2*h2 + h3*h3;
        #pragma unroll
        for (int m = 1; m <= 32; m <<= 1) {
            ssum += __shfl_xor(ssum, m, 64);
            ssq  += __shfl_xor(ssq, m, 64);
        }
        float mu = ssum * (1.0f / 256);
        float var = ssq * (1.0f / 256) - mu * mu;
        float rstd = rsqrtf(var + 1e-5f);
        float4 gp4 = *(const float4*)&g_post[c0];
        float4 bp4 = *(const float4*)&b_post[c0];
        float l0 = (h0 - mu) * rstd * gp4.x + bp4.x;
        float l1 = (h1 - mu) * rstd * gp4.y + bp4.y;
        float l2 = (h2 - mu) * rstd * gp4.z + bp4.z;
        float l3 = (h3 - mu) * rstd * gp4.w + bp4.w;
        unsigned short a0,c0s,a1,c1s,a2,c2s,a3,c3s;
        splitf(l0, a0, c0s); splitf(l1, a1, c1s);
        splitf(l2, a2, c2s); splitf(l3, a3, c3s);
        *(v4s*)&lnH[w * 264 + c0]  = (v4s){(short)a0,(short)a1,(short)a2,(short)a3};
        *(v4s*)&lnLo[w * 264 + c0] = (v4s){(short)c0s,(short)c1s,(short)c2s,(short)c3s};
        float4 hv4; hv4.x = h0; hv4.y = h1; hv4.z = h2; hv4.w = h3;
        *(float4*)&hnF[(size_t)row * 256 + c0] = hv4;
    }
    __syncthreads();

    // ---- phase C: MLP1 (32 tiles / 16 waves = 2 each) ----
    #pragma unroll
    for (int i = 0; i < 2; i++) {
        int ntile = w * 2 + i;
        int n = ntile * 16 + l16;
        v4f acc = (v4f){0.f, 0.f, 0.f, 0.f};
        #pragma unroll
        for (int kk = 0; kk < 8; kk++) {
            int ko = kk * 32 + quad * 8;
            v8s ah = *(const v8s*)&lnH[l16 * 264 + ko];
            v8s al = *(const v8s*)&lnLo[l16 * 264 + ko];
            v8s bh = *(const v8s*)&W1Th[(size_t)n * 256 + ko];
            v8s bl = *(const v8s*)&W1Tl[(size_t)n * 256 + ko];
            acc = __builtin_amdgcn_mfma_f32_16x16x32_bf16(al, bh, acc, 0, 0, 0);
            acc = __builtin_amdgcn_mfma_f32_16x16x32_bf16(ah, bl, acc, 0, 0, 0);
            acc = __builtin_amdgcn_mfma_f32_16x16x32_bf16(ah, bh, acc, 0, 0, 0);
        }
        float bb = b1[n];
        #pragma unroll
        for (int r = 0; r < 4; r++) {
            float y = fmaxf(acc[r] + bb, 0.0f);
            unsigned short hi, lo; splitf(y, hi, lo);
            y1H[(quad * 4 + r) * 520 + n]  = hi;
            y1Lo[(quad * 4 + r) * 520 + n] = lo;
        }
    }
    __syncthreads();

    // ---- phase D: MLP2 + residual (16 tiles / 16 waves = 1 each) ----
    {
        int n = w * 16 + l16;
        v4f acc = (v4f){0.f, 0.f, 0.f, 0.f};
        #pragma unroll
        for (int kk = 0; kk < 16; kk++) {
            int ko = kk * 32 + quad * 8;
            v8s ah = *(const v8s*)&y1H[l16 * 520 + ko];
            v8s al = *(const v8s*)&y1Lo[l16 * 520 + ko];
            v8s bh = *(const v8s*)&W2Th[(size_t)n * 512 + ko];
            v8s bl = *(const v8s*)&W2Tl[(size_t)n * 512 + ko];
            acc = __builtin_amdgcn_mfma_f32_16x16x32_bf16(al, bh, acc, 0, 0, 0);
            acc = __builtin_amdgcn_mfma_f32_16x16x32_bf16(ah, bl, acc, 0, 0, 0);
            acc = __builtin_amdgcn_mfma_f32_16x16x32_bf16(ah, bh, acc, 0, 0, 0);
        }
        float bb = b2[n];
        #pragma unroll
        for (int r = 0; r < 4; r++) {
            int m = m0 + quad * 4 + r;
            out[(size_t)m * 256 + n] = hnF[(size_t)m * 256 + n] + acc[r] + bb;
        }
    }
}

extern "C" void kernel_launch(void* const* d_in, const int* in_sizes, int n_in,
                              void* d_out, int out_size, void* d_ws, size_t ws_size,
                              hipStream_t stream) {
    const float* features = (const float*)d_in[0];
    const float* slots    = (const float*)d_in[1];
    const float* Wq   = (const float*)d_in[2];
    const float* bq   = (const float*)d_in[3];
    const float* Wk   = (const float*)d_in[4];
    const float* bk   = (const float*)d_in[5];
    const float* Wv   = (const float*)d_in[6];
    const float* bv   = (const float*)d_in[7];
    const float* W_ih = (const float*)d_in[8];
    const float* b_ih = (const float*)d_in[9];
    const float* W_hh = (const float*)d_in[10];
    const float* b_hh = (const float*)d_in[11];
    const float* g_pre  = (const float*)d_in[12];
    const float* b_pre  = (const float*)d_in[13];
    const float* g_post = (const float*)d_in[14];
    const float* b_post = (const float*)d_in[15];
    const float* W1 = (const float*)d_in[16];
    const float* b1 = (const float*)d_in[17];
    const float* W2 = (const float*)d_in[18];
    const float* b2 = (const float*)d_in[19];
    float* out = (float*)d_out;

    // ws layout (~3 MB): G f32 1.5MB (aliases qkT 256KB + qb, dead after
    // k_attn) | W1T/W2T hi/lo 4x256KB | WvT hi/lo 2x64KB | hnF 256KB
    char* wsb = (char*)d_ws;
    float* G               = (float*)wsb;
    unsigned short* qkT_ws = (unsigned short*)wsb;
    float* qb_ws           = (float*)(wsb + 262144);
    unsigned short* W1Th   = (unsigned short*)(wsb + 1572864);
    unsigned short* W1Tl   = (unsigned short*)(wsb + 1835008);
    unsigned short* W2Th   = (unsigned short*)(wsb + 2097152);
    unsigned short* W2Tl   = (unsigned short*)(wsb + 2359296);
    unsigned short* WvTH   = (unsigned short*)(wsb + 2621440);
    unsigned short* WvTl   = (unsigned short*)(wsb + 2686976);
    float* hnF             = (float*)(wsb + 2752512);
    float* agg_ws = out;   // agg accumulator in d_out (zeroed by K1 chunk0)

    k_prep<<<dim3(544), dim3(256), 0, stream>>>(
        slots, Wq, bq, g_pre, b_pre, Wk, bk, W1, W2, Wv,
        qkT_ws, qb_ws, W1Th, W1Tl, W2Th, W2Tl, WvTH, WvTl, agg_ws);
    k_attn<<<dim3(32, 32), dim3(256), 0, stream>>>(
        features, WvTH, WvTl, bv, qkT_ws, qb_ws, agg_ws);
    k_tail<<<dim3(16), dim3(1024), 0, stream>>>(
        slots, (const float*)out, W_ih, b_ih, W_hh, b_hh, g_post, b_post,
        W1Th, W1Tl, b1, W2Th, W2Tl, b2, G, hnF, out);
}

// Round 17
// 208.283 us; speedup vs baseline: 1.7781x; 1.1588x over previous
//
#include <hip/hip_runtime.h>
#include <hip/hip_bf16.h>

#define NSLOT 8
#define SDIM 256
#define FDIM 128
#define NHEAD 4
#define HDIM 64
#define NPOS 4096

typedef short v8s __attribute__((ext_vector_type(8)));
typedef short v4s __attribute__((ext_vector_type(4)));
typedef float v4f __attribute__((ext_vector_type(4)));

__device__ __forceinline__ unsigned short f2bf(float x) {
    __hip_bfloat16 h = __float2bfloat16(x);
    unsigned short u; __builtin_memcpy(&u, &h, 2); return u;
}
__device__ __forceinline__ float bfr2f(unsigned short u) {
    __hip_bfloat16 h; __builtin_memcpy(&h, &u, 2); return __bfloat162float(h);
}
__device__ __forceinline__ void splitf(float x, unsigned short& hi, unsigned short& lo) {
    hi = f2bf(x);
    lo = f2bf(x - bfr2f(hi));
}

// ---------------- K1 (fused prep, 592 blocks) — r12-verified:
//   blk   0..255: per-batch LN(slots)+q+qkT/qb, zero agg (b=blk>>3, chunk=blk&7)
//   blk 256..511: W1 / W2 transpose -> hi/lo bf16 [n][k]
//   blk 512..559: W_ih / W_hh (768x256 each) elementwise split -> hi/lo bf16
//   blk 560..591: Wv (128x256) transpose -> WvT hi/lo bf16 [256][128]
__global__ __launch_bounds__(256) void k_prep(
    const float* __restrict__ slots,
    const float* __restrict__ Wq, const float* __restrict__ bq,
    const float* __restrict__ g_pre, const float* __restrict__ b_pre,
    const float* __restrict__ Wk, const float* __restrict__ bk,
    const float* __restrict__ W1, const float* __restrict__ W2,
    const float* __restrict__ W_ih, const float* __restrict__ W_hh,
    const float* __restrict__ Wv,
    unsigned short* __restrict__ qkT_ws, float* __restrict__ qb_ws,
    unsigned short* __restrict__ W1Th, unsigned short* __restrict__ W1Tl,
    unsigned short* __restrict__ W2Th, unsigned short* __restrict__ W2Tl,
    unsigned short* __restrict__ WihH, unsigned short* __restrict__ WihL,
    unsigned short* __restrict__ WhhH, unsigned short* __restrict__ WhhL,
    unsigned short* __restrict__ WvTH, unsigned short* __restrict__ WvTl,
    float* __restrict__ agg_ws)
{
    int blk = blockIdx.x, t = threadIdx.x;
    __shared__ float s_ln[8 * 256];
    __shared__ float q_l[32 * 65];
    __shared__ float red1[256], red2[256];
    __shared__ float tl[32][33];

    if (blk >= 560) {                // WvT transpose+split (32 blocks)
        int id3 = blk - 560;
        int k0 = (id3 & 3) * 32, n0 = (id3 >> 2) * 32;
        for (int i = 0; i < 4; i++) {
            int idx = i * 256 + t, r = idx >> 5, c = idx & 31;
            tl[r][c] = Wv[(size_t)(k0 + r) * 256 + n0 + c];
        }
        __syncthreads();
        for (int i = 0; i < 4; i++) {
            int idx = i * 256 + t, r = idx >> 5, c = idx & 31;
            unsigned short hi, lo; splitf(tl[c][r], hi, lo);
            WvTH[(size_t)(n0 + r) * 128 + k0 + c] = hi;
            WvTl[(size_t)(n0 + r) * 128 + k0 + c] = lo;
        }
        return;
    }
    if (blk >= 512) {                // gate-weight split: 768 rows each (24 blocks each)
        int id2 = blk - 512;         // 0..47
        const float* src; unsigned short *dh, *dl; int r0;
        if (id2 < 24) { src = W_ih; dh = WihH; dl = WihL; r0 = id2 * 32; }
        else          { src = W_hh; dh = WhhH; dl = WhhL; r0 = (id2 - 24) * 32; }
        for (int i = 0; i < 32; i++) {
            size_t idx = (size_t)(r0 + i) * 256 + t;
            unsigned short hi, lo; splitf(src[idx], hi, lo);
            dh[idx] = hi; dl[idx] = lo;
        }
        return;
    }
    if (blk >= 256) {                // W1/W2 transpose+split
        int id = blk - 256;
        const float* src; unsigned short *dh, *dl; int N, K, k0, n0;
        if (id < 128) { src = W1; dh = W1Th; dl = W1Tl; N = 512; K = 256;
                        k0 = (id >> 4) * 32; n0 = (id & 15) * 32; }
        else          { int i2 = id - 128; src = W2; dh = W2Th; dl = W2Tl; N = 256; K = 512;
                        k0 = (i2 >> 3) * 32; n0 = (i2 & 7) * 32; }
        for (int i = 0; i < 4; i++) {
            int idx = i * 256 + t, r = idx >> 5, c = idx & 31;
            tl[r][c] = src[(size_t)(k0 + r) * N + n0 + c];
        }
        __syncthreads();
        for (int i = 0; i < 4; i++) {
            int idx = i * 256 + t, r = idx >> 5, c = idx & 31;
            unsigned short hi, lo; splitf(tl[c][r], hi, lo);
            dh[(size_t)(n0 + r) * K + k0 + c] = hi;
            dl[(size_t)(n0 + r) * K + k0 + c] = lo;
        }
        return;
    }

    // ---- per-batch prep ----
    int b = blk >> 3, chunk = blk & 7;
    if (chunk == 0)
        for (int i = 0; i < 8; i++) agg_ws[b * 2048 + i * 256 + t] = 0.0f;

    int s8 = t >> 5, lane = t & 31;
    float xv[8], sum = 0.0f, sq = 0.0f;
    for (int u = 0; u < 8; u++) {
        float x = slots[(b * 8 + s8) * 256 + lane * 8 + u];
        xv[u] = x; sum += x; sq += x * x;
    }
    red1[t] = sum; red2[t] = sq;
    __syncthreads();
    for (int o = 16; o > 0; o >>= 1) {
        if (lane < o) { red1[t] += red1[t + o]; red2[t] += red2[t + o]; }
        __syncthreads();
    }
    float mu  = red1[s8 * 32] * (1.0f / 256);
    float var = red2[s8 * 32] * (1.0f / 256) - mu * mu;
    float rstd = rsqrtf(var + 1e-5f);
    for (int u = 0; u < 8; u++) {
        int j = lane * 8 + u;
        s_ln[s8 * 256 + j] = (xv[u] - mu) * rstd * g_pre[j] + b_pre[j];
    }
    __syncthreads();

    float qa[8];
    #pragma unroll
    for (int s = 0; s < 8; s++) qa[s] = bq[t];
    for (int k = 0; k < 256; k++) {
        float wq = Wq[k * 256 + t];
        #pragma unroll
        for (int s = 0; s < 8; s++) qa[s] += s_ln[s * 256 + k] * wq;
    }
    int h = t >> 6, d = t & 63;
    for (int s = 0; s < 8; s++) q_l[(s * 4 + h) * 65 + d] = qa[s];
    __syncthreads();

    int hs = t & 31, hh = hs >> 3, si = hs & 7, c0 = t >> 5;
    const float* qrow = &q_l[(si * 4 + hh) * 65];
    for (int i = 0; i < 2; i++) {
        int c = chunk * 16 + i * 8 + c0;
        const float4* wk4 = (const float4*)&Wk[c * 256 + hh * 64];
        float acc = 0.0f;
        #pragma unroll
        for (int d4 = 0; d4 < 16; d4++) {
            float4 w = wk4[d4];
            acc += w.x * qrow[d4 * 4] + w.y * qrow[d4 * 4 + 1]
                 + w.z * qrow[d4 * 4 + 2] + w.w * qrow[d4 * 4 + 3];
        }
        qkT_ws[(b * 32 + hs) * 128 + c] = f2bf(acc);
    }
    if (chunk == 0 && t < 32) {
        int h2 = t >> 3, s2 = t & 7;
        float acc = 0.0f;
        for (int d2 = 0; d2 < 64; d2++)
            acc += bk[h2 * 64 + d2] * q_l[(s2 * 4 + h2) * 65 + d2];
        qb_ws[b * 32 + t] = acc;
    }
}

// ---------------- K2: MFMA scores + softmax + MFMA attF^T + MFMA epilogue --
__global__ __launch_bounds__(256, 4) void k_attn(
    const float* __restrict__ feat,   // (B,128,4096)
    const unsigned short* __restrict__ WvTH, const unsigned short* __restrict__ WvTl,
    const float* __restrict__ bv,
    const unsigned short* __restrict__ qkT, const float* __restrict__ qb_ws,
    float* __restrict__ agg_ws)
{
    __shared__ __align__(16) char smem[31360];
    unsigned short* featPC = (unsigned short*)smem;              // stride 136
    unsigned short* featCP = (unsigned short*)(smem + 8704);     // stride 56
    unsigned short* attFH  = (unsigned short*)smem;              // alias, stride 136
    unsigned short* attFL  = (unsigned short*)(smem + 8704);     // alias, stride 136
    float*          s_attn = (float*)(smem + 23040);             // stride 36
    unsigned short* s_aT   = (unsigned short*)(smem + 27648);    // stride 56
    float*          s_S    = (float*)(smem + 31232);

    int t = threadIdx.x, b = blockIdx.y, n0 = blockIdx.x * 128;
    int wv_ = t >> 6, lane = t & 63, quad = lane >> 4, l16 = lane & 15;
    int mt = wv_ >> 1, nt = wv_ & 1;
    int sp  = l16 + mt * 16;
    int shs = l16 + nt * 16;

    v8s bq_[4];
    #pragma unroll
    for (int ch = 0; ch < 4; ch++)
        bq_[ch] = *(const v8s*)&qkT[(b * 32 + shs) * 128 + ch * 32 + quad * 8];
    float qbv = qb_ws[b * 32 + shs];
    if (t < 32) s_S[t] = 0.0f;

    v4f accF[4];
    #pragma unroll
    for (int i = 0; i < 4; i++) accF[i] = (v4f){0.f, 0.f, 0.f, 0.f};

    int c0 = (t >> 3) * 4, p0 = (t & 7) * 4;

    for (int tt = 0; tt < 4; ++tt) {
        __syncthreads();
        int nb = n0 + tt * 32;
        float fv[4][4];
        #pragma unroll
        for (int r = 0; r < 4; r++) {
            float4 f = *(const float4*)&feat[(size_t)b * (FDIM * NPOS)
                                             + (size_t)(c0 + r) * NPOS + nb + p0];
            fv[r][0] = f.x; fv[r][1] = f.y; fv[r][2] = f.z; fv[r][3] = f.w;
        }
        #pragma unroll
        for (int r = 0; r < 4; r++)
            *(v4s*)&featCP[(c0 + r) * 56 + p0] =
                (v4s){(short)f2bf(fv[r][0]), (short)f2bf(fv[r][1]),
                      (short)f2bf(fv[r][2]), (short)f2bf(fv[r][3])};
        #pragma unroll
        for (int j = 0; j < 4; j++)
            *(v4s*)&featPC[(p0 + j) * 136 + c0] =
                (v4s){(short)f2bf(fv[0][j]), (short)f2bf(fv[1][j]),
                      (short)f2bf(fv[2][j]), (short)f2bf(fv[3][j])};
        __syncthreads();

        v4f acc = (v4f){0.f, 0.f, 0.f, 0.f};
        #pragma unroll
        for (int ch = 0; ch < 4; ch++) {
            v8s a = *(const v8s*)&featPC[sp * 136 + ch * 32 + quad * 8];
            acc = __builtin_amdgcn_mfma_f32_16x16x32_bf16(a, bq_[ch], acc, 0, 0, 0);
        }
        int pb = mt * 16 + quad * 4;
        #pragma unroll
        for (int r = 0; r < 4; r++)
            s_attn[(pb + r) * 36 + shs] = (acc[r] + qbv) * 0.125f;
        __syncthreads();

        if (t < 128) {
            int p = t >> 2, h2 = t & 3;
            float* a = &s_attn[p * 36 + h2 * 8];
            float m = a[0];
            for (int s = 1; s < 8; s++) m = fmaxf(m, a[s]);
            float e[8], ssum = 0.0f;
            for (int s = 0; s < 8; s++) { e[s] = __expf(a[s] - m); ssum += e[s]; }
            float inv = 1.0f / ssum;
            for (int s = 0; s < 8; s++)
                s_aT[(h2 * 8 + s) * 56 + p] = f2bf(e[s] * inv);
        }
        __syncthreads();

        v8s aA0 = *(const v8s*)&s_aT[l16 * 56 + quad * 8];
        v8s aA1 = *(const v8s*)&s_aT[(l16 + 16) * 56 + quad * 8];
        v8s bF0 = *(const v8s*)&featCP[(l16 + wv_ * 32) * 56 + quad * 8];
        v8s bF1 = *(const v8s*)&featCP[(l16 + wv_ * 32 + 16) * 56 + quad * 8];
        accF[0] = __builtin_amdgcn_mfma_f32_16x16x32_bf16(aA0, bF0, accF[0], 0, 0, 0);
        accF[1] = __builtin_amdgcn_mfma_f32_16x16x32_bf16(aA0, bF1, accF[1], 0, 0, 0);
        accF[2] = __builtin_amdgcn_mfma_f32_16x16x32_bf16(aA1, bF0, accF[2], 0, 0, 0);
        accF[3] = __builtin_amdgcn_mfma_f32_16x16x32_bf16(aA1, bF1, accF[3], 0, 0, 0);
        if (t < 32) {
            float ss = 0.0f;
            for (int p = 0; p < 32; p++) ss += bfr2f(s_aT[t * 56 + p]);
            s_S[t] += ss;
        }
    }
    __syncthreads();                 // feats views dead; alias as attFH/attFL
    #pragma unroll
    for (int mt2 = 0; mt2 < 2; mt2++)
        #pragma unroll
        for (int ntl = 0; ntl < 2; ntl++) {
            v4f f = accF[mt2 * 2 + ntl];
            int cc = wv_ * 32 + ntl * 16 + l16;
            #pragma unroll
            for (int r = 0; r < 4; r++) {
                unsigned short hi, lo; splitf(f[r], hi, lo);
                attFH[(mt2 * 16 + quad * 4 + r) * 136 + cc] = hi;
                attFL[(mt2 * 16 + quad * 4 + r) * 136 + cc] = lo;
            }
        }
    __syncthreads();

    int h = wv_;
    int am = h * 8 + (l16 & 7);
    for (int nt2 = 0; nt2 < 4; nt2++) {
        int n = h * 64 + nt2 * 16 + l16;
        v4f acc = (v4f){0.f, 0.f, 0.f, 0.f};
        #pragma unroll
        for (int kk = 0; kk < 4; kk++) {
            int ko = kk * 32 + quad * 8;
            v8s ah = *(const v8s*)&attFH[am * 136 + ko];
            v8s al = *(const v8s*)&attFL[am * 136 + ko];
            v8s bh = *(const v8s*)&WvTH[(size_t)n * 128 + ko];
            v8s bl = *(const v8s*)&WvTl[(size_t)n * 128 + ko];
            acc = __builtin_amdgcn_mfma_f32_16x16x32_bf16(al, bh, acc, 0, 0, 0);
            acc = __builtin_amdgcn_mfma_f32_16x16x32_bf16(ah, bl, acc, 0, 0, 0);
            acc = __builtin_amdgcn_mfma_f32_16x16x32_bf16(ah, bh, acc, 0, 0, 0);
        }
        float bvn = bv[n];
        if (quad < 2) {
            #pragma unroll
            for (int r = 0; r < 4; r++) {
                int s = quad * 4 + r;
                atomicAdd(&agg_ws[b * 2048 + s * 256 + n],
                          acc[r] + s_S[h * 8 + s] * bvn);
            }
        }
    }
}

// ---------------- K3: G[256][1536] = [x@W_ih^T + b_ih | h@W_hh^T + b_hh] ---
// r12-verified: 96 blocks (24 ntiles x 4 mtiles), precomputed hi/lo weights.
__global__ __launch_bounds__(256) void k_gate(
    const float* __restrict__ agg, const float* __restrict__ slots,
    const unsigned short* __restrict__ WihH, const unsigned short* __restrict__ WihL,
    const float* __restrict__ b_ih,
    const unsigned short* __restrict__ WhhH, const unsigned short* __restrict__ WhhL,
    const float* __restrict__ b_hh,
    float* __restrict__ G)
{
    int ntile = blockIdx.x, mtile = blockIdx.y, t = threadIdx.x;
    bool hhalf = ntile >= 12;
    int jbase = (hhalf ? ntile - 12 : ntile) * 64;
    const float* X = hhalf ? slots : agg;
    const unsigned short* BH = hhalf ? WhhH : WihH;
    const unsigned short* BL = hhalf ? WhhL : WihL;
    const float* bias = hhalf ? b_hh : b_ih;
    int gofs = hhalf ? 768 : 0;
    int m0 = mtile * 64;

    __shared__ __align__(16) unsigned short aH[64][264];
    __shared__ __align__(16) unsigned short aL[64][264];
    for (int i = 0; i < 16; i++) {
        int idx = i * 256 + t;
        int r = idx >> 6, q = idx & 63;
        float4 f = *(const float4*)&X[(size_t)(m0 + r) * 256 + q * 4];
        unsigned short h0,l0,h1,l1,h2,l2,h3,l3;
        splitf(f.x, h0, l0); splitf(f.y, h1, l1);
        splitf(f.z, h2, l2); splitf(f.w, h3, l3);
        *(v4s*)&aH[r][q * 4] = (v4s){(short)h0,(short)h1,(short)h2,(short)h3};
        *(v4s*)&aL[r][q * 4] = (v4s){(short)l0,(short)l1,(short)l2,(short)l3};
    }
    __syncthreads();

    int w = t >> 6, lane = t & 63, quad = lane >> 4, l16 = lane & 15;
    int am = w * 16 + l16;
    for (int s = 0; s < 4; s++) {
        int jrow = jbase + s * 16 + l16;     // 0..767
        v4f acc = (v4f){0.f, 0.f, 0.f, 0.f};
        #pragma unroll
        for (int kk = 0; kk < 8; kk++) {
            int ko = kk * 32 + quad * 8;
            v8s ah = *(const v8s*)&aH[am][ko];
            v8s al = *(const v8s*)&aL[am][ko];
            v8s bh = *(const v8s*)&BH[(size_t)jrow * 256 + ko];
            v8s bl = *(const v8s*)&BL[(size_t)jrow * 256 + ko];
            acc = __builtin_amdgcn_mfma_f32_16x16x32_bf16(al, bh, acc, 0, 0, 0);
            acc = __builtin_amdgcn_mfma_f32_16x16x32_bf16(ah, bl, acc, 0, 0, 0);
            acc = __builtin_amdgcn_mfma_f32_16x16x32_bf16(ah, bh, acc, 0, 0, 0);
        }
        float bv_ = bias[jrow];
        int gj = gofs + jbase + s * 16 + l16;
        #pragma unroll
        for (int r = 0; r < 4; r++)
            G[(size_t)(m0 + w * 16 + quad * 4 + r) * 1536 + gj] = acc[r] + bv_;
    }
}

__device__ __forceinline__ float gru1(float ir, float iz, float in_,
                                      float hr, float hz, float hn, float hp) {
    float r = 1.0f / (1.0f + __expf(-(ir + hr)));
    float z = 1.0f / (1.0f + __expf(-(iz + hz)));
    float n = tanhf(in_ + r * hn);
    return (1.0f - z) * n + z * hp;
}

// ---------------- K4: tail B-D — 16 blocks x 1024 threads (16 waves):
//   B: GRU + post-LN (1 row/wave) -> ln hi/lo (LDS), hn (global hnF)
//   C: MLP1 y1 = relu(ln@W1+b1) (32 tiles, 2/wave) -> y1 hi/lo (LDS)
//   D: MLP2 out = hn + y1@W2+b2 (16 tiles, 1/wave)
__global__ __launch_bounds__(1024) void k_tail2(
    const float* __restrict__ slots, const float* __restrict__ G,
    const float* __restrict__ g_post, const float* __restrict__ b_post,
    const unsigned short* __restrict__ W1Th, const unsigned short* __restrict__ W1Tl,
    const float* __restrict__ b1,
    const unsigned short* __restrict__ W2Th, const unsigned short* __restrict__ W2Tl,
    const float* __restrict__ b2,
    float* __restrict__ hnF, float* __restrict__ out)
{
    __shared__ __align__(16) char smem[50176];
    unsigned short* lnH   = (unsigned short*)smem;               // [16][264]
    unsigned short* lnLo  = (unsigned short*)(smem + 8448);
    unsigned short* y1H   = (unsigned short*)(smem + 16896);     // [16][520]
    unsigned short* y1Lo  = (unsigned short*)(smem + 33536);

    int t = threadIdx.x, m0 = blockIdx.x * 16;
    int w = t >> 6, lane = t & 63, quad = lane >> 4, l16 = lane & 15;

    // ---- phase B: GRU + LN, wave w -> row m0 + w ----
    {
        int row = m0 + w, c0 = lane * 4;
        const float* gp = &G[(size_t)row * 1536 + c0];
        float4 gir = *(const float4*)(gp);
        float4 giz = *(const float4*)(gp + 256);
        float4 gin = *(const float4*)(gp + 512);
        float4 ghr = *(const float4*)(gp + 768);
        float4 ghz = *(const float4*)(gp + 1024);
        float4 ghn = *(const float4*)(gp + 1280);
        float4 hp  = *(const float4*)&slots[(size_t)row * 256 + c0];
        float h0 = gru1(gir.x, giz.x, gin.x, ghr.x, ghz.x, ghn.x, hp.x);
        float h1 = gru1(gir.y, giz.y, gin.y, ghr.y, ghz.y, ghn.y, hp.y);
        float h2 = gru1(gir.z, giz.z, gin.z, ghr.z, ghz.z, ghn.z, hp.z);
        float h3 = gru1(gir.w, giz.w, gin.w, ghr.w, ghz.w, ghn.w, hp.w);
        float ssum = h0 + h1 + h2 + h3;
        float ssq  = h0*h0 + h1*h1 + h2*h2 + h3*h3;
        #pragma unroll
        for (int m = 1; m <= 32; m <<= 1) {
            ssum += __shfl_xor(ssum, m, 64);
            ssq  += __shfl_xor(ssq, m, 64);
        }
        float mu = ssum * (1.0f / 256);
        float var = ssq * (1.0f / 256) - mu * mu;
        float rstd = rsqrtf(var + 1e-5f);
        float4 gp4 = *(const float4*)&g_post[c0];
        float4 bp4 = *(const float4*)&b_post[c0];
        float l0 = (h0 - mu) * rstd * gp4.x + bp4.x;
        float l1 = (h1 - mu) * rstd * gp4.y + bp4.y;
        float l2 = (h2 - mu) * rstd * gp4.z + bp4.z;
        float l3 = (h3 - mu) * rstd * gp4.w + bp4.w;
        unsigned short a0,c0s,a1,c1s,a2,c2s,a3,c3s;
        splitf(l0, a0, c0s); splitf(l1, a1, c1s);
        splitf(l2, a2, c2s); splitf(l3, a3, c3s);
        *(v4s*)&lnH[w * 264 + c0]  = (v4s){(short)a0,(short)a1,(short)a2,(short)a3};
        *(v4s*)&lnLo[w * 264 + c0] = (v4s){(short)c0s,(short)c1s,(short)c2s,(short)c3s};
        float4 hv4; hv4.x = h0; hv4.y = h1; hv4.z = h2; hv4.w = h3;
        *(float4*)&hnF[(size_t)row * 256 + c0] = hv4;
    }
    __syncthreads();

    // ---- phase C: MLP1 (32 tiles / 16 waves = 2 each) ----
    #pragma unroll
    for (int i = 0; i < 2; i++) {
        int ntile = w * 2 + i;
        int n = ntile * 16 + l16;
        v4f acc = (v4f){0.f, 0.f, 0.f, 0.f};
        #pragma unroll
        for (int kk = 0; kk < 8; kk++) {
            int ko = kk * 32 + quad * 8;
            v8s ah = *(const v8s*)&lnH[l16 * 264 + ko];
            v8s al = *(const v8s*)&lnLo[l16 * 264 + ko];
            v8s bh = *(const v8s*)&W1Th[(size_t)n * 256 + ko];
            v8s bl = *(const v8s*)&W1Tl[(size_t)n * 256 + ko];
            acc = __builtin_amdgcn_mfma_f32_16x16x32_bf16(al, bh, acc, 0, 0, 0);
            acc = __builtin_amdgcn_mfma_f32_16x16x32_bf16(ah, bl, acc, 0, 0, 0);
            acc = __builtin_amdgcn_mfma_f32_16x16x32_bf16(ah, bh, acc, 0, 0, 0);
        }
        float bb = b1[n];
        #pragma unroll
        for (int r = 0; r < 4; r++) {
            float y = fmaxf(acc[r] + bb, 0.0f);
            unsigned short hi, lo; splitf(y, hi, lo);
            y1H[(quad * 4 + r) * 520 + n]  = hi;
            y1Lo[(quad * 4 + r) * 520 + n] = lo;
        }
    }
    __syncthreads();

    // ---- phase D: MLP2 + residual (16 tiles / 16 waves = 1 each) ----
    {
        int n = w * 16 + l16;
        v4f acc = (v4f){0.f, 0.f, 0.f, 0.f};
        #pragma unroll
        for (int kk = 0; kk < 16; kk++) {
            int ko = kk * 32 + quad * 8;
            v8s ah = *(const v8s*)&y1H[l16 * 520 + ko];
            v8s al = *(const v8s*)&y1Lo[l16 * 520 + ko];
            v8s bh = *(const v8s*)&W2Th[(size_t)n * 512 + ko];
            v8s bl = *(const v8s*)&W2Tl[(size_t)n * 512 + ko];
            acc = __builtin_amdgcn_mfma_f32_16x16x32_bf16(al, bh, acc, 0, 0, 0);
            acc = __builtin_amdgcn_mfma_f32_16x16x32_bf16(ah, bl, acc, 0, 0, 0);
            acc = __builtin_amdgcn_mfma_f32_16x16x32_bf16(ah, bh, acc, 0, 0, 0);
        }
        float bb = b2[n];
        #pragma unroll
        for (int r = 0; r < 4; r++) {
            int m = m0 + quad * 4 + r;
            out[(size_t)m * 256 + n] = hnF[(size_t)m * 256 + n] + acc[r] + bb;
        }
    }
}

extern "C" void kernel_launch(void* const* d_in, const int* in_sizes, int n_in,
                              void* d_out, int out_size, void* d_ws, size_t ws_size,
                              hipStream_t stream) {
    const float* features = (const float*)d_in[0];
    const float* slots    = (const float*)d_in[1];
    const float* Wq   = (const float*)d_in[2];
    const float* bq   = (const float*)d_in[3];
    const float* Wk   = (const float*)d_in[4];
    const float* bk   = (const float*)d_in[5];
    const float* Wv   = (const float*)d_in[6];
    const float* bv   = (const float*)d_in[7];
    const float* W_ih = (const float*)d_in[8];
    const float* b_ih = (const float*)d_in[9];
    const float* W_hh = (const float*)d_in[10];
    const float* b_hh = (const float*)d_in[11];
    const float* g_pre  = (const float*)d_in[12];
    const float* b_pre  = (const float*)d_in[13];
    const float* g_post = (const float*)d_in[14];
    const float* b_post = (const float*)d_in[15];
    const float* W1 = (const float*)d_in[16];
    const float* b1 = (const float*)d_in[17];
    const float* W2 = (const float*)d_in[18];
    const float* b2 = (const float*)d_in[19];
    float* out = (float*)d_out;

    // ws layout (~4.6 MB): G f32 1.5MB (aliases qkT 256KB + qb, dead after
    // k_attn) | W1T/W2T hi/lo 4x256KB | Wih/Whh hi/lo 4x384KB | WvT hi/lo
    // 2x64KB | hnF 256KB
    char* wsb = (char*)d_ws;
    float* G               = (float*)wsb;
    unsigned short* qkT_ws = (unsigned short*)wsb;
    float* qb_ws           = (float*)(wsb + 262144);
    unsigned short* W1Th   = (unsigned short*)(wsb + 1572864);
    unsigned short* W1Tl   = (unsigned short*)(wsb + 1835008);
    unsigned short* W2Th   = (unsigned short*)(wsb + 2097152);
    unsigned short* W2Tl   = (unsigned short*)(wsb + 2359296);
    unsigned short* WihH   = (unsigned short*)(wsb + 2621440);
    unsigned short* WihL   = (unsigned short*)(wsb + 3014656);
    unsigned short* WhhH   = (unsigned short*)(wsb + 3407872);
    unsigned short* WhhL   = (unsigned short*)(wsb + 3801088);
    unsigned short* WvTH   = (unsigned short*)(wsb + 4194304);
    unsigned short* WvTl   = (unsigned short*)(wsb + 4259840);
    float* hnF             = (float*)(wsb + 4325376);
    float* agg_ws = out;   // agg accumulator in d_out (zeroed by K1 chunk0)

    k_prep<<<dim3(592), dim3(256), 0, stream>>>(
        slots, Wq, bq, g_pre, b_pre, Wk, bk, W1, W2, W_ih, W_hh, Wv,
        qkT_ws, qb_ws, W1Th, W1Tl, W2Th, W2Tl,
        WihH, WihL, WhhH, WhhL, WvTH, WvTl, agg_ws);
    k_attn<<<dim3(32, 32), dim3(256), 0, stream>>>(
        features, WvTH, WvTl, bv, qkT_ws, qb_ws, agg_ws);
    k_gate<<<dim3(24, 4), dim3(256), 0, stream>>>(
        agg_ws, slots, WihH, WihL, b_ih, WhhH, WhhL, b_hh, G);
    k_tail2<<<dim3(16), dim3(1024), 0, stream>>>(
        slots, G, g_post, b_post, W1Th, W1Tl, b1, W2Th, W2Tl, b2, hnF, out);
}